// Round 9
// baseline (258.166 us; speedup 1.0000x reference)
//
#include <hip/hip_runtime.h>

#define NPOS    65536      // B*D*H*W
#define CDIM    64
#define KCODES  1024
#define SPATIAL 16384      // D*H*W
#define QELEMS  4194304    // B*C*D*H*W

#define PB      128        // positions per block
#define KT      128        // codes per tile
#define NTILE   8          // KCODES / KT

#define LOSS_IDX 1024      // wsf[0..1023] = code norms; wsf[1024] = loss accumulator

// sigma chunk swizzle: 16B chunk q (0..31) stored at chunk sig(q).
// Read pattern uses chunks {2m, 2m+1} -> cols 4m and 4m+64: bank starts 4m mod 32
// spread over 8 values -> 2-way (free). Staging writes also land 2-way.
__device__ __forceinline__ int sig(int q)  { return (q >> 1) | ((q & 1) << 4); }
__device__ __forceinline__ int xcol(int p) { return 4 * sig(p >> 2) + (p & 3); }

__global__ void k_norms(const float* __restrict__ emb, float* __restrict__ wsf) {
    const int k = blockIdx.x * 256 + threadIdx.x;   // grid covers exactly 1024
    if (k == 0) wsf[LOSS_IDX] = 0.0f;
    const float4* e4 = (const float4*)(emb + (size_t)k * CDIM);
    float s = 0.0f;
#pragma unroll
    for (int c = 0; c < CDIM / 4; ++c) {
        float4 e = e4[c];
        s += e.x * e.x + e.y * e.y + e.z * e.z + e.w * e.w;
    }
    wsf[k] = s;
}

// one x-scalar times 8 codes (ea = codes 8tx..+3, eb = 8tx+4..+7)
#define FMA_ROW(i, xs) \
    acc[i][0] = fmaf(xs, ea.x, acc[i][0]); acc[i][1] = fmaf(xs, ea.y, acc[i][1]); \
    acc[i][2] = fmaf(xs, ea.z, acc[i][2]); acc[i][3] = fmaf(xs, ea.w, acc[i][3]); \
    acc[i][4] = fmaf(xs, eb.x, acc[i][4]); acc[i][5] = fmaf(xs, eb.y, acc[i][5]); \
    acc[i][6] = fmaf(xs, eb.z, acc[i][6]); acc[i][7] = fmaf(xs, eb.w, acc[i][7]);

__global__ void k_fused(const float* __restrict__ z_e,
                        const float* __restrict__ emb,
                        float* __restrict__ out,
                        float* __restrict__ wsf) {
    __shared__ float XT[CDIM][PB];                // 32 KB  z_e tile, channel-major, sigma-swizzled pos chunks
    __shared__ float ET[CDIM][KT];                // 32 KB  E tile, channel-major, sigma-swizzled code chunks
    __shared__ float NRM[KCODES];                 // 4 KB
    __shared__ unsigned long long bestp[PB];      // 1 KB
    __shared__ int bi[PB];                        // 0.5 KB

    const int t    = threadIdx.x;
    const int tx   = t & 15;           // code group: codes 8tx..8tx+7 per tile
    const int ty   = t >> 4;           // pos group:  positions 8ty..8ty+7
    const int n0   = blockIdx.x * PB;
    const int b    = n0 >> 14;
    const int dhw0 = n0 & (SPATIAL - 1);
    const float* zb = z_e + (size_t)b * (CDIM * SPATIAL) + dhw0;

    // ---- stage X tile: coalesced 256B global reads (fixed c, consecutive p); 2-way LDS writes ----
#pragma unroll
    for (int i = 0; i < 32; ++i) {
        const int idx = i * 256 + t;
        const int c = idx >> 7, p = idx & 127;
        XT[c][xcol(p)] = zb[(size_t)c * SPATIAL + p];
    }
    // ---- stage norms ----
    *(float4*)&NRM[4 * t] = *(const float4*)(wsf + 4 * t);

    // ---- E staging mapping: thread owns code row crow, channel half cpart (wave-uniform cpart) ----
    const int crow  = t & 127;
    const int cpart = (t >> 7) << 5;   // 0 or 32
    const int ecol  = xcol(crow);
    float4 g0, g1, g2, g3, g4, g5, g6, g7;
    {
        const float* es = emb + (size_t)crow * CDIM + cpart;
        g0 = *(const float4*)(es +  0); g1 = *(const float4*)(es +  4);
        g2 = *(const float4*)(es +  8); g3 = *(const float4*)(es + 12);
        g4 = *(const float4*)(es + 16); g5 = *(const float4*)(es + 20);
        g6 = *(const float4*)(es + 24); g7 = *(const float4*)(es + 28);
    }

    unsigned long long best8[8];
#pragma unroll
    for (int i = 0; i < 8; ++i) best8[i] = ~0ull;

#pragma unroll 1
    for (int tile = 0; tile < NTILE; ++tile) {
        __syncthreads();   // prev compute done (ET free); covers XT/NRM staging on tile 0
        ET[cpart +  0][ecol] = g0.x; ET[cpart +  1][ecol] = g0.y;
        ET[cpart +  2][ecol] = g0.z; ET[cpart +  3][ecol] = g0.w;
        ET[cpart +  4][ecol] = g1.x; ET[cpart +  5][ecol] = g1.y;
        ET[cpart +  6][ecol] = g1.z; ET[cpart +  7][ecol] = g1.w;
        ET[cpart +  8][ecol] = g2.x; ET[cpart +  9][ecol] = g2.y;
        ET[cpart + 10][ecol] = g2.z; ET[cpart + 11][ecol] = g2.w;
        ET[cpart + 12][ecol] = g3.x; ET[cpart + 13][ecol] = g3.y;
        ET[cpart + 14][ecol] = g3.z; ET[cpart + 15][ecol] = g3.w;
        ET[cpart + 16][ecol] = g4.x; ET[cpart + 17][ecol] = g4.y;
        ET[cpart + 18][ecol] = g4.z; ET[cpart + 19][ecol] = g4.w;
        ET[cpart + 20][ecol] = g5.x; ET[cpart + 21][ecol] = g5.y;
        ET[cpart + 22][ecol] = g5.z; ET[cpart + 23][ecol] = g5.w;
        ET[cpart + 24][ecol] = g6.x; ET[cpart + 25][ecol] = g6.y;
        ET[cpart + 26][ecol] = g6.z; ET[cpart + 27][ecol] = g6.w;
        ET[cpart + 28][ecol] = g7.x; ET[cpart + 29][ecol] = g7.y;
        ET[cpart + 30][ecol] = g7.z; ET[cpart + 31][ecol] = g7.w;
        // prefetch next tile (latency hides under this tile's compute)
        if (tile + 1 < NTILE) {
            const float* es = emb + (size_t)((tile + 1) * KT + crow) * CDIM + cpart;
            g0 = *(const float4*)(es +  0); g1 = *(const float4*)(es +  4);
            g2 = *(const float4*)(es +  8); g3 = *(const float4*)(es + 12);
            g4 = *(const float4*)(es + 16); g5 = *(const float4*)(es + 20);
            g6 = *(const float4*)(es + 24); g7 = *(const float4*)(es + 28);
        }
        __syncthreads();   // ET ready

        float acc[8][8];
#pragma unroll
        for (int i = 0; i < 8; ++i)
#pragma unroll
            for (int j = 0; j < 8; ++j) acc[i][j] = 0.0f;

        for (int g = 0; g < 16; ++g) {
#pragma unroll
            for (int cj = 0; cj < 4; ++cj) {
                const int ch = 4 * g + cj;          // channel ascending 0..63 (bit-exact order)
                const float4 ea = *(const float4*)&ET[ch][4 * tx];        // codes 8tx..+3
                const float4 eb = *(const float4*)&ET[ch][4 * tx + 64];   // codes 8tx+4..+7
                const float4 xa = *(const float4*)&XT[ch][4 * ty];        // pos 8ty..+3
                const float4 xb = *(const float4*)&XT[ch][4 * ty + 64];   // pos 8ty+4..+7
                FMA_ROW(0, xa.x) FMA_ROW(1, xa.y) FMA_ROW(2, xa.z) FMA_ROW(3, xa.w)
                FMA_ROW(4, xb.x) FMA_ROW(5, xb.y) FMA_ROW(6, xb.z) FMA_ROW(7, xb.w)
            }
        }

        // scores + running argmin (global k in minor bits => numpy first-occurrence tie-break)
        const float4 nra = *(const float4*)&NRM[tile * KT + 8 * tx];
        const float4 nrb = *(const float4*)&NRM[tile * KT + 8 * tx + 4];
        const float nv[8] = {nra.x, nra.y, nra.z, nra.w, nrb.x, nrb.y, nrb.z, nrb.w};
#pragma unroll
        for (int j = 0; j < 8; ++j) {
            const unsigned gk = (unsigned)(tile * KT + 8 * tx + j);
#pragma unroll
            for (int i = 0; i < 8; ++i) {
                const float s = fmaf(-2.0f, acc[i][j], nv[j]);
                unsigned u    = __float_as_uint(s);
                unsigned mono = (u & 0x80000000u) ? ~u : (u | 0x80000000u);
                unsigned long long pk = ((unsigned long long)mono << 10) | gk;
                if (pk < best8[i]) best8[i] = pk;
            }
        }
    }

    // ---- reduce argmin across the 16 tx lanes (xor within the low-4-bit field) ----
#pragma unroll
    for (int off = 1; off < 16; off <<= 1)
#pragma unroll
        for (int i = 0; i < 8; ++i) {
            unsigned long long o = __shfl_xor(best8[i], off, 64);
            if (o < best8[i]) best8[i] = o;
        }
    if (tx == 0)
#pragma unroll
        for (int i = 0; i < 8; ++i) bestp[8 * ty + i] = best8[i];
    __syncthreads();

    // ---- indices ----
    if (t < PB) {
        const int bx = (int)(bestp[t] & 1023ull);
        bi[t] = bx;
        out[QELEMS + 2 + n0 + t] = (float)bx;
    }
    __syncthreads();

    // ---- fused epilogue: gather e (L2-hot), quantize on the fly, loss, coalesced writes ----
    float lsum = 0.0f;
    float* qb = out + (size_t)b * (CDIM * SPATIAL) + dhw0;
#pragma unroll
    for (int i = 0; i < 32; ++i) {
        const int idx = i * 256 + t;
        const int c = idx >> 7, p = idx & 127;
        const float xv = XT[c][xcol(p)];
        const float ev = emb[(size_t)bi[p] * CDIM + c];
        const float d  = ev - xv;                       // quantized - z_e (f32)
        qb[(size_t)c * SPATIAL + p] = xv + d;           // straight-through arithmetic
        lsum = fmaf(d, d, lsum);
    }
#pragma unroll
    for (int off = 32; off > 0; off >>= 1) lsum += __shfl_down(lsum, off, 64);
    if ((t & 63) == 0) atomicAdd(&wsf[LOSS_IDX], lsum);
}

__global__ void k_loss(const float* __restrict__ wsf, float* __restrict__ out) {
    const float m = wsf[LOSS_IDX] / (float)QELEMS;
    out[QELEMS]     = m;  // codebook_loss
    out[QELEMS + 1] = m;  // commitment_loss (same forward value)
}

extern "C" void kernel_launch(void* const* d_in, const int* in_sizes, int n_in,
                              void* d_out, int out_size, void* d_ws, size_t ws_size,
                              hipStream_t stream) {
    const float* z_e = (const float*)d_in[0];
    const float* emb = (const float*)d_in[1];
    float*       out = (float*)d_out;
    float*       wsf = (float*)d_ws;

    k_norms<<<KCODES / 256, 256, 0, stream>>>(emb, wsf);      // also zeroes loss accum
    k_fused<<<NPOS / PB, 256, 0, stream>>>(z_e, emb, out, wsf);
    k_loss<<<1, 1, 0, stream>>>(wsf, out);
}

// Round 10
// 210.488 us; speedup vs baseline: 1.2265x; 1.2265x over previous
//
#include <hip/hip_runtime.h>

#define NPOS    65536      // B*D*H*W
#define CDIM    64
#define KCODES  1024
#define SPATIAL 16384      // D*H*W
#define QELEMS  4194304    // B*C*D*H*W

#define PB      128        // positions per block
#define KT      128        // codes per tile
#define NTILE   8          // KCODES / KT
#define NBLK    (NPOS / PB)

// ws layout: wsf[0] = loss accumulator (f32); ((unsigned*)ws)[1] = completion counter
// both zeroed by an 8-byte hipMemsetAsync before launch.

// sigma chunk swizzle: 16B chunk q (0..31) stored at chunk sig(q).
// All staging writes / compute reads / epilogue reads land <=2-way on banks (free, m136).
__device__ __forceinline__ int sig(int q)  { return (q >> 1) | ((q & 1) << 4); }
__device__ __forceinline__ int xcol(int p) { return 4 * sig(p >> 2) + (p & 3); }

// one x-scalar times 8 codes (ea = codes 8tx..+3, eb = 8tx+4..+7)
#define FMA_ROW(i, xs) \
    acc[i][0] = fmaf(xs, ea.x, acc[i][0]); acc[i][1] = fmaf(xs, ea.y, acc[i][1]); \
    acc[i][2] = fmaf(xs, ea.z, acc[i][2]); acc[i][3] = fmaf(xs, ea.w, acc[i][3]); \
    acc[i][4] = fmaf(xs, eb.x, acc[i][4]); acc[i][5] = fmaf(xs, eb.y, acc[i][5]); \
    acc[i][6] = fmaf(xs, eb.z, acc[i][6]); acc[i][7] = fmaf(xs, eb.w, acc[i][7]);

__global__ __launch_bounds__(256, 2) void k_fused(const float* __restrict__ z_e,
                                                  const float* __restrict__ emb,
                                                  float* __restrict__ out,
                                                  float* __restrict__ wsf,
                                                  unsigned* __restrict__ cnt) {
    __shared__ float XT[CDIM][PB];                // 32 KB  z_e tile, channel-major, sigma-swizzled pos chunks
    __shared__ float ET[CDIM][KT];                // 32 KB  E tile, channel-major, sigma-swizzled code chunks
    __shared__ float NRM[KCODES];                 // 4 KB
    __shared__ unsigned long long bestp[PB];      // 1 KB
    __shared__ int bi[PB];                        // 0.5 KB

    const int t    = threadIdx.x;
    const int tx   = t & 15;           // code group: codes 8tx..8tx+7 per tile
    const int ty   = t >> 4;           // pos group:  positions 8ty..8ty+7
    const int n0   = blockIdx.x * PB;
    const int b    = n0 >> 14;
    const int dhw0 = n0 & (SPATIAL - 1);
    const float* zb = z_e + (size_t)b * (CDIM * SPATIAL) + dhw0;

    // ---- stage X tile: coalesced 256B global reads (fixed c, consecutive p); 2-way LDS writes ----
#pragma unroll
    for (int i = 0; i < 32; ++i) {
        const int idx = i * 256 + t;
        const int c = idx >> 7, p = idx & 127;
        XT[c][xcol(p)] = zb[(size_t)c * SPATIAL + p];
    }

    // ---- in-block code norms (emb is L2-hot; same summation expression as the verified k_norms) ----
#pragma unroll
    for (int j = 0; j < 4; ++j) {
        const int k = t + 256 * j;
        const float4* e4 = (const float4*)(emb + (size_t)k * CDIM);
        float s = 0.0f;
#pragma unroll
        for (int c = 0; c < CDIM / 4; ++c) {
            float4 e = e4[c];
            s += e.x * e.x + e.y * e.y + e.z * e.z + e.w * e.w;
        }
        NRM[k] = s;
    }

    // ---- E staging mapping: thread owns code row crow, channel half cpart (wave-uniform cpart) ----
    const int crow  = t & 127;
    const int cpart = (t >> 7) << 5;   // 0 or 32
    const int ecol  = xcol(crow);
    float4 g0, g1, g2, g3, g4, g5, g6, g7;
    {
        const float* es = emb + (size_t)crow * CDIM + cpart;
        g0 = *(const float4*)(es +  0); g1 = *(const float4*)(es +  4);
        g2 = *(const float4*)(es +  8); g3 = *(const float4*)(es + 12);
        g4 = *(const float4*)(es + 16); g5 = *(const float4*)(es + 20);
        g6 = *(const float4*)(es + 24); g7 = *(const float4*)(es + 28);
    }

    unsigned long long best8[8];
#pragma unroll
    for (int i = 0; i < 8; ++i) best8[i] = ~0ull;

#pragma unroll 1
    for (int tile = 0; tile < NTILE; ++tile) {
        __syncthreads();   // prev compute done (ET free); covers XT/NRM staging on tile 0
        ET[cpart +  0][ecol] = g0.x; ET[cpart +  1][ecol] = g0.y;
        ET[cpart +  2][ecol] = g0.z; ET[cpart +  3][ecol] = g0.w;
        ET[cpart +  4][ecol] = g1.x; ET[cpart +  5][ecol] = g1.y;
        ET[cpart +  6][ecol] = g1.z; ET[cpart +  7][ecol] = g1.w;
        ET[cpart +  8][ecol] = g2.x; ET[cpart +  9][ecol] = g2.y;
        ET[cpart + 10][ecol] = g2.z; ET[cpart + 11][ecol] = g2.w;
        ET[cpart + 12][ecol] = g3.x; ET[cpart + 13][ecol] = g3.y;
        ET[cpart + 14][ecol] = g3.z; ET[cpart + 15][ecol] = g3.w;
        ET[cpart + 16][ecol] = g4.x; ET[cpart + 17][ecol] = g4.y;
        ET[cpart + 18][ecol] = g4.z; ET[cpart + 19][ecol] = g4.w;
        ET[cpart + 20][ecol] = g5.x; ET[cpart + 21][ecol] = g5.y;
        ET[cpart + 22][ecol] = g5.z; ET[cpart + 23][ecol] = g5.w;
        ET[cpart + 24][ecol] = g6.x; ET[cpart + 25][ecol] = g6.y;
        ET[cpart + 26][ecol] = g6.z; ET[cpart + 27][ecol] = g6.w;
        ET[cpart + 28][ecol] = g7.x; ET[cpart + 29][ecol] = g7.y;
        ET[cpart + 30][ecol] = g7.z; ET[cpart + 31][ecol] = g7.w;
        // prefetch next tile (latency hides under this tile's compute)
        if (tile + 1 < NTILE) {
            const float* es = emb + (size_t)((tile + 1) * KT + crow) * CDIM + cpart;
            g0 = *(const float4*)(es +  0); g1 = *(const float4*)(es +  4);
            g2 = *(const float4*)(es +  8); g3 = *(const float4*)(es + 12);
            g4 = *(const float4*)(es + 16); g5 = *(const float4*)(es + 20);
            g6 = *(const float4*)(es + 24); g7 = *(const float4*)(es + 28);
        }
        __syncthreads();   // ET ready

        float acc[8][8];
#pragma unroll
        for (int i = 0; i < 8; ++i)
#pragma unroll
            for (int j = 0; j < 8; ++j) acc[i][j] = 0.0f;

        for (int g = 0; g < 16; ++g) {
#pragma unroll
            for (int cj = 0; cj < 4; ++cj) {
                const int ch = 4 * g + cj;          // channel ascending 0..63 (bit-exact order)
                const float4 ea = *(const float4*)&ET[ch][4 * tx];        // codes 8tx..+3
                const float4 eb = *(const float4*)&ET[ch][4 * tx + 64];   // codes 8tx+4..+7
                const float4 xa = *(const float4*)&XT[ch][4 * ty];        // pos 8ty..+3
                const float4 xb = *(const float4*)&XT[ch][4 * ty + 64];   // pos 8ty+4..+7
                FMA_ROW(0, xa.x) FMA_ROW(1, xa.y) FMA_ROW(2, xa.z) FMA_ROW(3, xa.w)
                FMA_ROW(4, xb.x) FMA_ROW(5, xb.y) FMA_ROW(6, xb.z) FMA_ROW(7, xb.w)
            }
        }

        // scores + running argmin (global k in minor bits => numpy first-occurrence tie-break)
        const float4 nra = *(const float4*)&NRM[tile * KT + 8 * tx];
        const float4 nrb = *(const float4*)&NRM[tile * KT + 8 * tx + 4];
        const float nv[8] = {nra.x, nra.y, nra.z, nra.w, nrb.x, nrb.y, nrb.z, nrb.w};
#pragma unroll
        for (int j = 0; j < 8; ++j) {
            const unsigned gk = (unsigned)(tile * KT + 8 * tx + j);
#pragma unroll
            for (int i = 0; i < 8; ++i) {
                const float s = fmaf(-2.0f, acc[i][j], nv[j]);
                unsigned u    = __float_as_uint(s);
                unsigned mono = (u & 0x80000000u) ? ~u : (u | 0x80000000u);
                unsigned long long pk = ((unsigned long long)mono << 10) | gk;
                if (pk < best8[i]) best8[i] = pk;
            }
        }
    }

    // ---- reduce argmin across the 16 tx lanes (xor within the low-4-bit field) ----
#pragma unroll
    for (int off = 1; off < 16; off <<= 1)
#pragma unroll
        for (int i = 0; i < 8; ++i) {
            unsigned long long o = __shfl_xor(best8[i], off, 64);
            if (o < best8[i]) best8[i] = o;
        }
    if (tx == 0)
#pragma unroll
        for (int i = 0; i < 8; ++i) bestp[8 * ty + i] = best8[i];
    __syncthreads();

    // ---- indices ----
    if (t < PB) {
        const int bx = (int)(bestp[t] & 1023ull);
        bi[t] = bx;
        out[QELEMS + 2 + n0 + t] = (float)bx;
    }
    __syncthreads();

    // ---- fused epilogue: gather e (L2-hot), quantize on the fly, loss, coalesced writes ----
    float lsum = 0.0f;
    float* qb = out + (size_t)b * (CDIM * SPATIAL) + dhw0;
#pragma unroll
    for (int i = 0; i < 32; ++i) {
        const int idx = i * 256 + t;
        const int c = idx >> 7, p = idx & 127;
        const float xv = XT[c][xcol(p)];
        const float ev = emb[(size_t)bi[p] * CDIM + c];
        const float d  = ev - xv;                       // quantized - z_e (f32)
        qb[(size_t)c * SPATIAL + p] = xv + d;           // straight-through arithmetic
        lsum = fmaf(d, d, lsum);
    }
#pragma unroll
    for (int off = 32; off > 0; off >>= 1) lsum += __shfl_down(lsum, off, 64);
    if ((t & 63) == 0) atomicAdd(&wsf[0], lsum);

    // ---- last block writes the two loss outputs (device-scope counter handshake) ----
    __syncthreads();                    // all 4 waves' loss atomics issued+drained (waitcnt before barrier)
    if (t == 0) {
        __threadfence();                // make this block's atomic visible device-wide
        const unsigned old = atomicAdd(cnt, 1u);
        if (old == NBLK - 1) {
            const float tot = atomicAdd(&wsf[0], 0.0f);   // atomic read: coherent view
            const float m   = tot / (float)QELEMS;
            out[QELEMS]     = m;        // codebook_loss
            out[QELEMS + 1] = m;        // commitment_loss (same forward value)
        }
    }
}

extern "C" void kernel_launch(void* const* d_in, const int* in_sizes, int n_in,
                              void* d_out, int out_size, void* d_ws, size_t ws_size,
                              hipStream_t stream) {
    const float* z_e = (const float*)d_in[0];
    const float* emb = (const float*)d_in[1];
    float*       out = (float*)d_out;
    float*       wsf = (float*)d_ws;
    unsigned*    cnt = (unsigned*)d_ws + 1;

    hipMemsetAsync(d_ws, 0, 8, stream);   // loss accum + completion counter
    k_fused<<<NBLK, 256, 0, stream>>>(z_e, emb, out, wsf, cnt);
}